// Round 16
// baseline (604.219 us; speedup 1.0000x reference)
//
#include <hip/hip_runtime.h>
#include <hip/hip_cooperative_groups.h>

namespace cg = cooperative_groups;

// ---------------------------------------------------------------------------
// GCN pipeline, round 16: ONE cooperative kernel, 7 grid-strided phases
// (round-12 measured-best bodies verbatim), grid.sync() between phases.
// Rounds 13-15 flat within 2%: each kernel is at its access-pattern floor;
// the residual over the ~30us HBM floor is dispatch gaps + per-kernel
// ramp/drain. Mono-kernel removes 6 launch boundaries; weights load once
// per phase (not per block).
//   P1 hist (2048-edge tiles, 512 buckets of 256 nodes) -> P2 scanTiles ->
//   P3 multisplit (scan1 once/block; counting sort) -> P4 place_fine ->
//   P5 agg_xin -> P6 transform12 -> P7 agg2_fc.
// ---------------------------------------------------------------------------

#define MS_TILE 2048
#define MAXB 512
#define AGG_STAGE 1024
#define SMEM_BYTES 19712

struct GcnParams {
    const float* x;
    const int* src;
    const int* dst;
    const float* W1; const float* b1;
    const float* W2; const float* b2;
    const float* fcW1; const float* fcb1;
    const float* fcW2; const float* fcb2;
    float* out;
    int* histG; int* offsG; int* btot; int* gbase;
    unsigned* binned; int* offs; float* dinv;
    float* y; float* z; float* h2; int* srcs;
    int n, E, nTiles, NBkt;
};

__global__ __launch_bounds__(256) void gcn_mono(GcnParams p) {
    cg::grid_group grid = cg::this_grid();
    __shared__ __align__(16) unsigned char smem[SMEM_BYTES];
    int t = threadIdx.x;
    int G = gridDim.x;

    // ---------------- P1: per-tile histogram of dst>>8 ----------------
    {
        int* h = (int*)smem;
        for (int tile = blockIdx.x; tile < p.nTiles; tile += G) {
            h[t] = 0;
            h[t + 256] = 0;
            __syncthreads();
            int base = tile * MS_TILE;
            int cnt = min(MS_TILE, p.E - base);
            for (int k = t; k < cnt; k += 256) atomicAdd(&h[p.dst[base + k] >> 8], 1);
            __syncthreads();
            p.histG[tile * MAXB + t] = h[t];         // thread t reads only h[t],
            p.histG[tile * MAXB + 256 + t] = h[t + 256];  // h[t+256] -> re-zero safe
        }
    }
    grid.sync();

    // ---------------- P2: per-bucket scan of counts across tiles ----------------
    {
        int* scn = (int*)smem;
        for (int b = blockIdx.x; b < MAXB; b += G) {
            int run = 0;
            for (int base = 0; base < p.nTiles; base += 256) {
                int idx = base + t;
                int v = (idx < p.nTiles) ? p.histG[idx * MAXB + b] : 0;
                scn[t] = v;
                __syncthreads();
                int incl = v;
                for (int d = 1; d < 256; d <<= 1) {
                    int add = (t >= d) ? scn[t - d] : 0;
                    __syncthreads();
                    incl += add;
                    scn[t] = incl;
                    __syncthreads();
                }
                if (idx < p.nTiles) p.offsG[idx * MAXB + b] = incl - v + run;
                run += scn[255];
                __syncthreads();
            }
            if (t == 0) p.btot[b] = run;
        }
    }
    grid.sync();

    // ---------------- P3: counting sort into 256-node buckets ----------------
    {
        unsigned* stage = (unsigned*)smem;                      // 8192 B
        unsigned short* sb = (unsigned short*)(smem + 8192);    // 4096 B
        int* hoff = (int*)(smem + 12288);                       // 2056 B
        int* hcur = (int*)(smem + 14344);                       // 2048 B
        int* gb   = (int*)(smem + 16392);                       // 2048 B
        int* scn  = (int*)(smem + 18440);                       // 1024 B
        // scan 1 (once per block): bucket totals -> global bases
        int b0 = p.btot[2 * t], b1v = p.btot[2 * t + 1];
        int s2 = b0 + b1v;
        scn[t] = s2;
        __syncthreads();
        int incl2 = s2;
        for (int d = 1; d < 256; d <<= 1) {
            int add = (t >= d) ? scn[t - d] : 0;
            __syncthreads();
            incl2 += add;
            scn[t] = incl2;
            __syncthreads();
        }
        int ex2a = incl2 - s2;
        int ex2b = ex2a + b0;
        if (blockIdx.x == 0) {
            p.gbase[2 * t] = ex2a;
            p.gbase[2 * t + 1] = ex2b;
            if (t == 255) p.gbase[MAXB] = p.E;
        }
        for (int tile = blockIdx.x; tile < p.nTiles; tile += G) {
            int base = tile * MS_TILE;
            int cnt = min(MS_TILE, p.E - base);
            int a0 = p.histG[tile * MAXB + 2 * t];
            int a1 = p.histG[tile * MAXB + 2 * t + 1];
            int s = a0 + a1;
            scn[t] = s;            // disjoint from prior iter's stage/sb/gb/hoff reads
            __syncthreads();
            int incl = s;
            for (int d = 1; d < 256; d <<= 1) {
                int add = (t >= d) ? scn[t - d] : 0;
                __syncthreads();
                incl += add;
                scn[t] = incl;
                __syncthreads();
            }
            int ex = incl - s;
            hoff[2 * t] = ex;
            hoff[2 * t + 1] = ex + a0;
            hcur[2 * t] = ex;
            hcur[2 * t + 1] = ex + a0;
            gb[2 * t] = ex2a + p.offsG[tile * MAXB + 2 * t];
            gb[2 * t + 1] = ex2b + p.offsG[tile * MAXB + 2 * t + 1];
            if (t == 255) hoff[MAXB] = cnt;
            __syncthreads();
            for (int k = t; k < cnt; k += 256) {
                int d = p.dst[base + k];
                int b = d >> 8;
                int q = atomicAdd(&hcur[b], 1);
                stage[q] = ((unsigned)p.src[base + k] << 8) | (unsigned)(d & 255);
                sb[q] = (unsigned short)b;
            }
            __syncthreads();
            for (int k = t; k < cnt; k += 256) {
                int b = sb[k];
                p.binned[gb[b] + (k - hoff[b])] = stage[k];
            }
        }
    }
    grid.sync();

    // ---------------- P4: per-bucket CSR (offs, dinv, y, srcs) ----------------
    {
        int* cnt  = (int*)smem;
        int* scn  = (int*)(smem + 1024);
        int* lcur = (int*)(smem + 2048);
        for (int b = blockIdx.x; b < p.NBkt; b += G) {
            int node0 = b << 8;
            int nn = min(256, p.n - node0);
            int e0 = p.gbase[b], e1 = p.gbase[b + 1];
            cnt[t] = 0;
            __syncthreads();
            for (int k = e0 + t; k < e1; k += 256)
                atomicAdd(&cnt[p.binned[k] & 255u], 1);
            __syncthreads();
            int c = cnt[t];
            scn[t] = c;
            __syncthreads();
            int incl = c;
            for (int d = 1; d < 256; d <<= 1) {
                int add = (t >= d) ? scn[t - d] : 0;
                __syncthreads();
                incl += add;
                scn[t] = incl;
                __syncthreads();
            }
            int myoff = e0 + (incl - c);
            lcur[t] = myoff;
            if (t < nn) {
                int node = node0 + t;
                p.offs[node] = myoff;
                float di = 1.0f / sqrtf((float)(c + 1));  // +1 self loop
                p.dinv[node] = di;
                const float* xr = p.x + (size_t)node * 5;
                float4 va = {xr[0] * di, xr[1] * di, xr[2] * di, xr[3] * di};
                float4 vb = {xr[4] * di, 0.f, 0.f, 0.f};
                *(float4*)(p.y + (size_t)node * 8) = va;
                *(float4*)(p.y + (size_t)node * 8 + 4) = vb;
            }
            __syncthreads();
            for (int k = e0 + t; k < e1; k += 256) {
                unsigned w = p.binned[k];
                int q = atomicAdd(&lcur[w & 255u], 1);
                p.srcs[q] = (int)(w >> 8);
            }
            __syncthreads();  // protect cnt re-zero vs straggler lcur atomics ordering
        }
    }
    grid.sync();

    // ---------------- P5: layer-1 aggregate in 5-dim space -> z ----------------
    {
        const float4* yv = (const float4*)p.y;
        for (int i = blockIdx.x * 256 + t; i < p.n; i += G * 256) {
            float4 a = yv[(size_t)i * 2];
            float4 b = yv[(size_t)i * 2 + 1];
            int off = p.offs[i];
            int cnt = ((i + 1 < p.n) ? p.offs[i + 1] : p.E) - off;
            int q = 0;
            for (; q + 4 <= cnt; q += 4) {
                int s0 = p.srcs[off + q], s1 = p.srcs[off + q + 1];
                int s2 = p.srcs[off + q + 2], s3 = p.srcs[off + q + 3];
                float4 v0 = yv[(size_t)s0 * 2];
                float4 w0 = yv[(size_t)s0 * 2 + 1];
                float4 v1 = yv[(size_t)s1 * 2];
                float4 w1 = yv[(size_t)s1 * 2 + 1];
                float4 v2 = yv[(size_t)s2 * 2];
                float4 w2 = yv[(size_t)s2 * 2 + 1];
                float4 v3 = yv[(size_t)s3 * 2];
                float4 w3 = yv[(size_t)s3 * 2 + 1];
                a.x += (v0.x + v1.x) + (v2.x + v3.x);
                a.y += (v0.y + v1.y) + (v2.y + v3.y);
                a.z += (v0.z + v1.z) + (v2.z + v3.z);
                a.w += (v0.w + v1.w) + (v2.w + v3.w);
                b.x += (w0.x + w1.x) + (w2.x + w3.x);
            }
            for (; q < cnt; ++q) {
                int s0 = p.srcs[off + q];
                float4 v0 = yv[(size_t)s0 * 2];
                float w0 = p.y[(size_t)s0 * 8 + 4];
                a.x += v0.x; a.y += v0.y; a.z += v0.z; a.w += v0.w;
                b.x += w0;
            }
            float di = p.dinv[i];
            float4 oa = {a.x * di, a.y * di, a.z * di, a.w * di};
            float4 ob = {b.x * di, 0.f, 0.f, 0.f};
            ((float4*)p.z)[(size_t)i * 2] = oa;
            ((float4*)p.z)[(size_t)i * 2 + 1] = ob;
        }
    }
    grid.sync();

    // ---------------- P6: fused transforms z -> h2 ----------------
    {
        float* w1s = (float*)smem;            // 1280 B
        float* b1s = (float*)(smem + 1280);   // 256 B
        float* w2s = (float*)(smem + 1536);   // 8192 B
        float* o1  = (float*)(smem + 9728);   // 8192 B
        w1s[t] = p.W1[t];
        if (t < 64) {
            w1s[t + 256] = p.W1[t + 256];
            b1s[t] = p.b1[t];
        }
#pragma unroll
        for (int r = 0; r < 8; ++r) w2s[r * 256 + t] = p.W2[r * 256 + t];
        __syncthreads();
        int nChunks = (p.n + 31) / 32;
        for (int c = blockIdx.x; c < nChunks; c += G) {
            int node0 = c * 32;
#pragma unroll
            for (int r = 0; r < 8; ++r) {
                int idx = r * 256 + t;
                int li = idx >> 6, f = idx & 63;
                int i = node0 + li;
                if (i < p.n) {
                    const float* zr = p.z + (size_t)i * 8;
                    float acc = b1s[f];
#pragma unroll
                    for (int k = 0; k < 5; ++k) acc += zr[k] * w1s[k * 64 + f];
                    o1[li * 64 + f] = fmaxf(acc, 0.0f);
                }
            }
            __syncthreads();
#pragma unroll
            for (int r = 0; r < 4; ++r) {
                int idx = r * 256 + t;
                int li = idx >> 5, g = idx & 31;
                int i = node0 + li;
                if (i < p.n) {
                    float acc = 0.f;
#pragma unroll
                    for (int k = 0; k < 64; ++k)
                        acc += o1[li * 64 + k] * w2s[k * 32 + g];
                    p.h2[(size_t)i * 32 + g] = acc * p.dinv[i];
                }
            }
            __syncthreads();  // before next chunk overwrites o1
        }
    }
    grid.sync();

    // ---------------- P7: layer-2 aggregate + FC head ----------------
    {
        int* sidx  = (int*)smem;              // 4096 B
        float* sm  = (float*)(smem + 4096);   // 4224 B (32 x 33)
        float* x3s = (float*)(smem + 8320);   // 2048 B
        float* w1s = (float*)(smem + 10368);  // 2048 B
        float* w2s = (float*)(smem + 12416);  // 128 B
        float* b1s = (float*)(smem + 12544);  // 64 B
        float* b2s = (float*)(smem + 12608);  // 8 B
        float* bs2 = (float*)(smem + 12624);  // 128 B
        w1s[t] = p.fcW1[t];
        w1s[t + 256] = p.fcW1[t + 256];
        if (t < 32) { w2s[t] = p.fcW2[t]; bs2[t] = p.b2[t]; }
        if (t < 16) b1s[t] = p.fcb1[t];
        if (t < 2) b2s[t] = p.fcb2[t];
        __syncthreads();
        const char* hb = (const char*)p.h2;
        int li = t >> 3, fq = t & 7;
        int nBlk = (p.n + 31) / 32;
        for (int bb = blockIdx.x; bb < nBlk; bb += G) {
            int node0 = bb * 32;
            int i = node0 + li;
            bool live = (i < p.n);
            int e0 = p.offs[node0];
            int eEnd = (node0 + 32 < p.n) ? p.offs[node0 + 32] : p.E;
            int myOff = 0, myCnt = 0;
            float4 acc = {0.f, 0.f, 0.f, 0.f};
            if (live) {
                myOff = p.offs[i];
                myCnt = ((i + 1 < p.n) ? p.offs[i + 1] : p.E) - myOff;
                acc = *(const float4*)(hb + ((size_t)i << 7) + (fq << 4));
            }
            for (int cs = e0; cs < eEnd; cs += AGG_STAGE) {
                int ce = min(cs + AGG_STAGE, eEnd);
                for (int k = cs + t; k < ce; k += 256) sidx[k - cs] = p.srcs[k] << 7;
                __syncthreads();
                int ps = max(myOff, cs), pe = min(myOff + myCnt, ce);
                int q = ps;
                for (; q + 8 <= pe; q += 8) {
                    int o[8];
#pragma unroll
                    for (int u = 0; u < 8; ++u) o[u] = sidx[q + u - cs];
                    float4 v[8];
#pragma unroll
                    for (int u = 0; u < 8; ++u)
                        v[u] = *(const float4*)(hb + o[u] + (fq << 4));
#pragma unroll
                    for (int u = 0; u < 8; ++u) {
                        acc.x += v[u].x; acc.y += v[u].y;
                        acc.z += v[u].z; acc.w += v[u].w;
                    }
                }
                for (; q + 4 <= pe; q += 4) {
                    int o0 = sidx[q - cs], o1 = sidx[q + 1 - cs];
                    int o2 = sidx[q + 2 - cs], o3 = sidx[q + 3 - cs];
                    float4 v0 = *(const float4*)(hb + o0 + (fq << 4));
                    float4 v1 = *(const float4*)(hb + o1 + (fq << 4));
                    float4 v2 = *(const float4*)(hb + o2 + (fq << 4));
                    float4 v3 = *(const float4*)(hb + o3 + (fq << 4));
                    acc.x += (v0.x + v1.x) + (v2.x + v3.x);
                    acc.y += (v0.y + v1.y) + (v2.y + v3.y);
                    acc.z += (v0.z + v1.z) + (v2.z + v3.z);
                    acc.w += (v0.w + v1.w) + (v2.w + v3.w);
                }
                for (; q < pe; ++q) {
                    float4 v = *(const float4*)(hb + sidx[q - cs] + (fq << 4));
                    acc.x += v.x; acc.y += v.y; acc.z += v.z; acc.w += v.w;
                }
                __syncthreads();
            }
            if (live) {
                float di = p.dinv[i];
                int f0 = fq << 2;
                sm[li * 33 + f0 + 0] = fmaxf(di * acc.x + bs2[f0 + 0], 0.f);
                sm[li * 33 + f0 + 1] = fmaxf(di * acc.y + bs2[f0 + 1], 0.f);
                sm[li * 33 + f0 + 2] = fmaxf(di * acc.z + bs2[f0 + 2], 0.f);
                sm[li * 33 + f0 + 3] = fmaxf(di * acc.w + bs2[f0 + 3], 0.f);
            }
            __syncthreads();
#pragma unroll
            for (int r = 0; r < 2; ++r) {
                int idx = r * 256 + t;
                int lj = idx >> 4, j = idx & 15;
                if (node0 + lj < p.n) {
                    float a = b1s[j];
#pragma unroll
                    for (int k = 0; k < 32; ++k)
                        a += sm[lj * 33 + k] * w1s[k * 16 + j];
                    x3s[lj * 16 + j] = fmaxf(a, 0.f);
                }
            }
            __syncthreads();
            if (t < 64) {
                int lj = t >> 1, o = t & 1;
                if (node0 + lj < p.n) {
                    float a = b2s[o];
#pragma unroll
                    for (int j = 0; j < 16; ++j)
                        a += x3s[lj * 16 + j] * w2s[j * 2 + o];
                    p.out[(size_t)(node0 + lj) * 2 + o] = a;
                }
            }
            __syncthreads();  // protect x3s/sm reuse before next iteration
        }
    }
}

extern "C" void kernel_launch(void* const* d_in, const int* in_sizes, int n_in,
                              void* d_out, int out_size, void* d_ws, size_t ws_size,
                              hipStream_t stream) {
    GcnParams p;
    p.x    = (const float*)d_in[0];
    const int* edge_index = (const int*)d_in[1];
    p.W1   = (const float*)d_in[2];
    p.b1   = (const float*)d_in[3];
    p.W2   = (const float*)d_in[4];
    p.b2   = (const float*)d_in[5];
    p.fcW1 = (const float*)d_in[6];
    p.fcb1 = (const float*)d_in[7];
    p.fcW2 = (const float*)d_in[8];
    p.fcb2 = (const float*)d_in[9];
    p.out  = (float*)d_out;

    p.n = in_sizes[0] / 5;
    p.E = in_sizes[1] / 2;
    p.NBkt = (p.n + 255) >> 8;                     // 391
    p.nTiles = (p.E + MS_TILE - 1) / MS_TILE;      // 782
    p.src = edge_index;
    p.dst = edge_index + p.E;

    char* ws = (char*)d_ws;
    auto alloc = [&](size_t bytes) {
        char* q = ws;
        ws += (bytes + 255) & ~(size_t)255;
        return q;
    };
    p.offs   = (int*)alloc((size_t)p.n * 4);
    p.dinv   = (float*)alloc((size_t)p.n * 4);
    p.histG  = (int*)alloc((size_t)p.nTiles * MAXB * 4);
    p.offsG  = (int*)alloc((size_t)p.nTiles * MAXB * 4);
    p.btot   = (int*)alloc((size_t)MAXB * 4);
    p.gbase  = (int*)alloc((size_t)(MAXB + 1) * 4);
    p.srcs   = (int*)alloc((size_t)p.E * 4);
    p.binned = (unsigned*)alloc((size_t)p.E * 4);
    p.y      = (float*)alloc((size_t)p.n * 8 * 4);
    p.z      = (float*)alloc((size_t)p.n * 8 * 4);
    p.h2     = (float*)alloc((size_t)p.n * 32 * 4);

    // co-residency-safe grid (deterministic across calls -> graph-safe)
    int maxPerCU = 0;
    hipOccupancyMaxActiveBlocksPerMultiprocessor(&maxPerCU, (const void*)gcn_mono,
                                                 256, 0);
    if (maxPerCU < 1) maxPerCU = 1;
    int grid = maxPerCU * 256;            // 256 CUs on MI355X
    if (grid > 768) grid = 768;           // 3 blocks/CU target

    void* args[] = {&p};
    hipLaunchCooperativeKernel((void*)gcn_mono, dim3(grid), dim3(256), args, 0,
                               stream);
}

// Round 17
// 186.142 us; speedup vs baseline: 3.2460x; 3.2460x over previous
//
#include <hip/hip_runtime.h>

// ---------------------------------------------------------------------------
// GCN pipeline, round 17 (round-12 revert + one fusion at safe granularity):
//   histA -> scanTiles -> multisplit2 (counting sort + folded base scan) ->
//   place_fine2 (per-node CSR offs + dinv + y) -> agg1_t12 (FUSED: 5-dim
//   gather (8 thr/node, shfl-reduce) -> z in LDS -> W1/relu/W2 -> h2) ->
//   agg2_fc (layer-2 aggregate + FC head).
// Round-16 lesson: mono-kernel = one worst-case launch config for all
// phases (VGPR 56, 768 blocks, grid.sync spins) -> 3x regression. Fusions
// must keep per-phase-appropriate grids. agg1_t12 fuses at transform12's
// 3125-block granularity (round-9's 391-block fusion starved waves; this
// one keeps ~8 blocks/CU resident).
// ---------------------------------------------------------------------------

#define MS_TILE 2048
#define MAXB 512  // padded coarse-bucket count (NBkt = ceil(n/256) <= 512)
#define AGG_NODES 32
#define AGG_STAGE 1024

// per-tile LDS histogram of dst>>8 -> histG[tile*512 + b] (coalesced rows)
__global__ __launch_bounds__(256) void histA(const int* __restrict__ dst,
                                             int* __restrict__ histG, int E) {
    __shared__ int h[MAXB];
    int t = threadIdx.x;
    h[t] = 0;
    h[t + 256] = 0;
    __syncthreads();
    int base = blockIdx.x * MS_TILE;
    int cnt = min(MS_TILE, E - base);
    for (int k = t; k < cnt; k += 256) atomicAdd(&h[dst[base + k] >> 8], 1);
    __syncthreads();
    histG[blockIdx.x * MAXB + t] = h[t];
    histG[blockIdx.x * MAXB + 256 + t] = h[t + 256];
}

// one block per bucket b: exclusive scan of histG[.][b] across tiles ->
// offsG[tile*512+b]; bucket total -> bucketTotal[b]
__global__ __launch_bounds__(256) void scanTiles(const int* __restrict__ histG,
                                                 int* __restrict__ offsG,
                                                 int* __restrict__ bucketTotal,
                                                 int nTiles) {
    __shared__ int scn[256];
    int b = blockIdx.x, t = threadIdx.x;
    int run = 0;
    for (int base = 0; base < nTiles; base += 256) {
        int idx = base + t;
        int v = (idx < nTiles) ? histG[idx * MAXB + b] : 0;
        scn[t] = v;
        __syncthreads();
        int incl = v;
        for (int d = 1; d < 256; d <<= 1) {
            int add = (t >= d) ? scn[t - d] : 0;
            __syncthreads();
            incl += add;
            scn[t] = incl;
            __syncthreads();
        }
        if (idx < nTiles) offsG[idx * MAXB + b] = incl - v + run;
        run += scn[255];
        __syncthreads();
    }
    if (t == 0) bucketTotal[b] = run;
}

// Deterministic tile counting-sort. Payload: (src<<8)|(dst&255).
// Also scans bucketTotal -> global bucket bases; tile 0 publishes gbase.
__global__ __launch_bounds__(256) void multisplit2(
    const int* __restrict__ src, const int* __restrict__ dst,
    const int* __restrict__ histG, const int* __restrict__ offsG,
    const int* __restrict__ btot, int* __restrict__ gbaseOut,
    unsigned* __restrict__ binned, int E) {
    __shared__ unsigned stage[MS_TILE];
    __shared__ unsigned short sb[MS_TILE];
    __shared__ int hoff[MAXB + 1];
    __shared__ int hcur[MAXB];
    __shared__ int gb[MAXB];
    __shared__ int scn[256];
    int t = threadIdx.x;
    int tile = blockIdx.x;
    int base = tile * MS_TILE;
    int cnt = min(MS_TILE, E - base);

    // scan 1: bucket totals -> global bucket bases
    int b0 = btot[2 * t], b1v = btot[2 * t + 1];
    int s2 = b0 + b1v;
    scn[t] = s2;
    __syncthreads();
    int incl2 = s2;
    for (int d = 1; d < 256; d <<= 1) {
        int add = (t >= d) ? scn[t - d] : 0;
        __syncthreads();
        incl2 += add;
        scn[t] = incl2;
        __syncthreads();
    }
    int ex2 = incl2 - s2;
    gb[2 * t] = ex2 + offsG[tile * MAXB + 2 * t];
    gb[2 * t + 1] = ex2 + b0 + offsG[tile * MAXB + 2 * t + 1];
    if (tile == 0) {
        gbaseOut[2 * t] = ex2;
        gbaseOut[2 * t + 1] = ex2 + b0;
        if (t == 255) gbaseOut[MAXB] = E;
    }

    // scan 2: per-tile hist -> LDS stage layout
    int a0 = histG[tile * MAXB + 2 * t];
    int a1 = histG[tile * MAXB + 2 * t + 1];
    int s = a0 + a1;
    scn[t] = s;
    __syncthreads();
    int incl = s;
    for (int d = 1; d < 256; d <<= 1) {
        int add = (t >= d) ? scn[t - d] : 0;
        __syncthreads();
        incl += add;
        scn[t] = incl;
        __syncthreads();
    }
    int ex = incl - s;
    hoff[2 * t] = ex;
    hoff[2 * t + 1] = ex + a0;
    hcur[2 * t] = ex;
    hcur[2 * t + 1] = ex + a0;
    if (t == 255) hoff[MAXB] = cnt;
    __syncthreads();
    for (int k = t; k < cnt; k += 256) {
        int d = dst[base + k];
        int b = d >> 8;
        int p = atomicAdd(&hcur[b], 1);
        stage[p] = ((unsigned)src[base + k] << 8) | (unsigned)(d & 255);
        sb[p] = (unsigned short)b;
    }
    __syncthreads();
    for (int k = t; k < cnt; k += 256) {
        int b = sb[k];
        binned[gb[b] + (k - hoff[b])] = stage[k];
    }
}

// Per coarse bucket: per-node deg via LDS count, LDS scan -> offs, dinv,
// y[i,:] = dinv[i]*x[i,:] (padded to 8 floats), then exact CSR scatter.
__global__ __launch_bounds__(256) void place_fine2(
    const unsigned* __restrict__ binned, const int* __restrict__ gbase,
    const float* __restrict__ x, int* __restrict__ offs,
    float* __restrict__ dinv, float* __restrict__ y, int* __restrict__ srcs, int n) {
    __shared__ int cnt[256];
    __shared__ int scn[256];
    __shared__ int lcur[256];
    int t = threadIdx.x, b = blockIdx.x;
    int node0 = b << 8;
    int nn = min(256, n - node0);
    int e0 = gbase[b], e1 = gbase[b + 1];
    cnt[t] = 0;
    __syncthreads();
    for (int k = e0 + t; k < e1; k += 256) atomicAdd(&cnt[binned[k] & 255u], 1);
    __syncthreads();
    int c = cnt[t];
    scn[t] = c;
    __syncthreads();
    int incl = c;
    for (int d = 1; d < 256; d <<= 1) {
        int add = (t >= d) ? scn[t - d] : 0;
        __syncthreads();
        incl += add;
        scn[t] = incl;
        __syncthreads();
    }
    int myoff = e0 + (incl - c);
    lcur[t] = myoff;
    if (t < nn) {
        int node = node0 + t;
        offs[node] = myoff;
        float di = 1.0f / sqrtf((float)(c + 1));  // +1 self loop
        dinv[node] = di;
        const float* xr = x + (size_t)node * 5;
        float4 a = {xr[0] * di, xr[1] * di, xr[2] * di, xr[3] * di};
        float4 bq = {xr[4] * di, 0.f, 0.f, 0.f};
        *(float4*)(y + (size_t)node * 8) = a;
        *(float4*)(y + (size_t)node * 8 + 4) = bq;
    }
    __syncthreads();
    for (int k = e0 + t; k < e1; k += 256) {
        unsigned w = binned[k];
        int p = atomicAdd(&lcur[w & 255u], 1);
        srcs[p] = (int)(w >> 8);
    }
}

// FUSED layer-1 aggregate + both transforms, at 32-node granularity
// (3125 blocks, ~8 blocks/CU). Gather: 8 threads/node, ~2 edges each,
// shfl-xor reduce within the in-wave 8-lane group; z lives only in LDS
// (zs stride 6, slot 5 = dinv). Then o1 = relu(z@W1+b1), h2 = dinv*(o1@W2).
__global__ __launch_bounds__(256) void agg1_t12(
    const float* __restrict__ y, const int* __restrict__ srcs,
    const int* __restrict__ offs, const float* __restrict__ dinv,
    const float* __restrict__ W1, const float* __restrict__ b1,
    const float* __restrict__ W2, float* __restrict__ h2, int n, int E) {
    __shared__ float w1s[320];
    __shared__ float b1s[64];
    __shared__ float w2s[64 * 32];
    __shared__ float o1[32 * 64];
    __shared__ float zs[32 * 6];
    int t = threadIdx.x;
    w1s[t] = W1[t];
    if (t < 64) {
        w1s[t + 256] = W1[t + 256];
        b1s[t] = b1[t];
    }
#pragma unroll
    for (int r = 0; r < 8; ++r) w2s[r * 256 + t] = W2[r * 256 + t];

    int node0 = blockIdx.x * 32;
    int li = t >> 3, e = t & 7;  // node-in-block, edge-lane
    int i = node0 + li;
    const float4* yv = (const float4*)y;
    float4 a = {0.f, 0.f, 0.f, 0.f};
    float b0 = 0.f;
    if (i < n) {
        int off = offs[i];
        int cnt = ((i + 1 < n) ? offs[i + 1] : E) - off;
        if (e == 0) {  // self-loop term once per node
            a = yv[(size_t)i * 2];
            b0 = y[(size_t)i * 8 + 4];
        }
        for (int p = e; p < cnt; p += 8) {
            int s = srcs[off + p];
            float4 v = yv[(size_t)s * 2];
            float w = y[(size_t)s * 8 + 4];
            a.x += v.x; a.y += v.y; a.z += v.z; a.w += v.w;
            b0 += w;
        }
    }
    // reduce the 8-lane group (lanes t..t|7 are in one wave, one node)
#pragma unroll
    for (int m = 4; m >= 1; m >>= 1) {
        a.x += __shfl_xor(a.x, m, 64);
        a.y += __shfl_xor(a.y, m, 64);
        a.z += __shfl_xor(a.z, m, 64);
        a.w += __shfl_xor(a.w, m, 64);
        b0  += __shfl_xor(b0, m, 64);
    }
    if (i < n && e == 0) {
        float di = dinv[i];
        zs[li * 6 + 0] = a.x * di;
        zs[li * 6 + 1] = a.y * di;
        zs[li * 6 + 2] = a.z * di;
        zs[li * 6 + 3] = a.w * di;
        zs[li * 6 + 4] = b0 * di;
        zs[li * 6 + 5] = di;
    }
    __syncthreads();  // zs + weights visible
    // o1 = relu(z@W1 + b1): 32 nodes x 64 feats
#pragma unroll
    for (int r = 0; r < 8; ++r) {
        int idx = r * 256 + t;
        int lj = idx >> 6, f = idx & 63;
        if (node0 + lj < n) {
            const float* zr = zs + lj * 6;
            float acc = b1s[f];
#pragma unroll
            for (int k = 0; k < 5; ++k) acc += zr[k] * w1s[k * 64 + f];
            o1[lj * 64 + f] = fmaxf(acc, 0.0f);
        }
    }
    __syncthreads();
    // h2 = dinv*(o1@W2): 32 nodes x 32 feats
#pragma unroll
    for (int r = 0; r < 4; ++r) {
        int idx = r * 256 + t;
        int lj = idx >> 5, g = idx & 31;
        int i2 = node0 + lj;
        if (i2 < n) {
            float acc = 0.f;
#pragma unroll
            for (int k = 0; k < 64; ++k) acc += o1[lj * 64 + k] * w2s[k * 32 + g];
            h2[(size_t)i2 * 32 + g] = acc * zs[lj * 6 + 5];
        }
    }
}

// FUSED layer-2 aggregate + FC head (round-12 measured best). Block = 32
// nodes x 8 f4-groups; LDS-staged CSR indices, 8-deep float4 gather unroll.
__global__ __launch_bounds__(256) void agg2_fc(
    const float* __restrict__ h, const int* __restrict__ srcs,
    const int* __restrict__ offs, const float* __restrict__ dinv,
    const float* __restrict__ b2, const float* __restrict__ fcW1,
    const float* __restrict__ fcb1, const float* __restrict__ fcW2,
    const float* __restrict__ fcb2, float* __restrict__ out, int n, int E) {
    __shared__ int sidx[AGG_STAGE];
    __shared__ float sm[AGG_NODES * 33];  // out2, stride-33 padded
    __shared__ float x3s[AGG_NODES * 16];
    __shared__ float w1s[512];
    __shared__ float w2s[32];
    __shared__ float b1s[16];
    __shared__ float b2s[2];
    __shared__ float bs2[32];
    int t = threadIdx.x;
    w1s[t] = fcW1[t];
    w1s[t + 256] = fcW1[t + 256];
    if (t < 32) { w2s[t] = fcW2[t]; bs2[t] = b2[t]; }
    if (t < 16) b1s[t] = fcb1[t];
    if (t < 2) b2s[t] = fcb2[t];

    int node0 = blockIdx.x * AGG_NODES;
    int li = t >> 3, fq = t & 7;  // node-in-block, 4-feature group
    int i = node0 + li;
    bool live = (i < n);
    const char* hb = (const char*)h;

    int e0 = offs[node0];
    int eEnd = (node0 + AGG_NODES < n) ? offs[node0 + AGG_NODES] : E;
    int myOff = 0, myCnt = 0;
    float4 acc = {0.f, 0.f, 0.f, 0.f};
    if (live) {
        myOff = offs[i];
        myCnt = ((i + 1 < n) ? offs[i + 1] : E) - myOff;
        acc = *(const float4*)(hb + ((size_t)i << 7) + (fq << 4));  // self-loop
    }

    for (int cs = e0; cs < eEnd; cs += AGG_STAGE) {
        int ce = min(cs + AGG_STAGE, eEnd);
        for (int k = cs + t; k < ce; k += 256) sidx[k - cs] = srcs[k] << 7;
        __syncthreads();
        int ps = max(myOff, cs), pe = min(myOff + myCnt, ce);
        int p = ps;
        for (; p + 8 <= pe; p += 8) {
            int o[8];
#pragma unroll
            for (int u = 0; u < 8; ++u) o[u] = sidx[p + u - cs];
            float4 v[8];
#pragma unroll
            for (int u = 0; u < 8; ++u)
                v[u] = *(const float4*)(hb + o[u] + (fq << 4));
#pragma unroll
            for (int u = 0; u < 8; ++u) {
                acc.x += v[u].x; acc.y += v[u].y;
                acc.z += v[u].z; acc.w += v[u].w;
            }
        }
        for (; p + 4 <= pe; p += 4) {
            int o0 = sidx[p - cs], o1 = sidx[p + 1 - cs];
            int o2 = sidx[p + 2 - cs], o3 = sidx[p + 3 - cs];
            float4 v0 = *(const float4*)(hb + o0 + (fq << 4));
            float4 v1 = *(const float4*)(hb + o1 + (fq << 4));
            float4 v2 = *(const float4*)(hb + o2 + (fq << 4));
            float4 v3 = *(const float4*)(hb + o3 + (fq << 4));
            acc.x += (v0.x + v1.x) + (v2.x + v3.x);
            acc.y += (v0.y + v1.y) + (v2.y + v3.y);
            acc.z += (v0.z + v1.z) + (v2.z + v3.z);
            acc.w += (v0.w + v1.w) + (v2.w + v3.w);
        }
        for (; p < pe; ++p) {
            float4 v = *(const float4*)(hb + sidx[p - cs] + (fq << 4));
            acc.x += v.x; acc.y += v.y; acc.z += v.z; acc.w += v.w;
        }
        __syncthreads();
    }

    if (live) {
        float di = dinv[i];
        int f0 = fq << 2;
        sm[li * 33 + f0 + 0] = fmaxf(di * acc.x + bs2[f0 + 0], 0.f);
        sm[li * 33 + f0 + 1] = fmaxf(di * acc.y + bs2[f0 + 1], 0.f);
        sm[li * 33 + f0 + 2] = fmaxf(di * acc.z + bs2[f0 + 2], 0.f);
        sm[li * 33 + f0 + 3] = fmaxf(di * acc.w + bs2[f0 + 3], 0.f);
    }
    __syncthreads();
#pragma unroll
    for (int r = 0; r < 2; ++r) {
        int idx = r * 256 + t;
        int lj = idx >> 4, j = idx & 15;
        if (node0 + lj < n) {
            float a = b1s[j];
#pragma unroll
            for (int k = 0; k < 32; ++k) a += sm[lj * 33 + k] * w1s[k * 16 + j];
            x3s[lj * 16 + j] = fmaxf(a, 0.f);
        }
    }
    __syncthreads();
    if (t < 64) {
        int lj = t >> 1, o = t & 1;
        if (node0 + lj < n) {
            float a = b2s[o];
#pragma unroll
            for (int j = 0; j < 16; ++j) a += x3s[lj * 16 + j] * w2s[j * 2 + o];
            out[(size_t)(node0 + lj) * 2 + o] = a;
        }
    }
}

extern "C" void kernel_launch(void* const* d_in, const int* in_sizes, int n_in,
                              void* d_out, int out_size, void* d_ws, size_t ws_size,
                              hipStream_t stream) {
    const float* edge_attr = (const float*)d_in[0];
    const int* edge_index  = (const int*)d_in[1];
    const float* W1   = (const float*)d_in[2];
    const float* b1   = (const float*)d_in[3];
    const float* W2   = (const float*)d_in[4];
    const float* b2   = (const float*)d_in[5];
    const float* fcW1 = (const float*)d_in[6];
    const float* fcb1 = (const float*)d_in[7];
    const float* fcW2 = (const float*)d_in[8];
    const float* fcb2 = (const float*)d_in[9];
    float* out = (float*)d_out;

    int n = in_sizes[0] / 5;
    int E = in_sizes[1] / 2;
    int NBkt = (n + 255) >> 8;                 // 391 for n=100000 (<= MAXB)
    int nTiles = (E + MS_TILE - 1) / MS_TILE;  // 782
    const int* src = edge_index;
    const int* dst = edge_index + E;

    char* ws = (char*)d_ws;
    auto alloc = [&](size_t bytes) {
        char* p = ws;
        ws += (bytes + 255) & ~(size_t)255;
        return p;
    };
    int*      offs   = (int*)alloc((size_t)n * 4);
    float*    dinv   = (float*)alloc((size_t)n * 4);
    int*      histG  = (int*)alloc((size_t)nTiles * MAXB * 4);
    int*      offsG  = (int*)alloc((size_t)nTiles * MAXB * 4);
    int*      btot   = (int*)alloc((size_t)MAXB * 4);
    int*      gbase  = (int*)alloc((size_t)(MAXB + 1) * 4);
    int*      srcs   = (int*)alloc((size_t)E * 4);
    unsigned* binned = (unsigned*)alloc((size_t)E * 4);
    float*    y      = (float*)alloc((size_t)n * 8 * 4);
    float*    h2     = (float*)alloc((size_t)n * 32 * 4);

    histA<<<nTiles, 256, 0, stream>>>(dst, histG, E);
    scanTiles<<<MAXB, 256, 0, stream>>>(histG, offsG, btot, nTiles);
    multisplit2<<<nTiles, 256, 0, stream>>>(src, dst, histG, offsG, btot, gbase,
                                            binned, E);
    place_fine2<<<NBkt, 256, 0, stream>>>(binned, gbase, edge_attr, offs, dinv,
                                          y, srcs, n);
    agg1_t12<<<(n + 31) / 32, 256, 0, stream>>>(y, srcs, offs, dinv, W1, b1, W2,
                                                h2, n, E);
    agg2_fc<<<(n + AGG_NODES - 1) / AGG_NODES, 256, 0, stream>>>(
        h2, srcs, offs, dinv, b2, fcW1, fcb1, fcW2, fcb2, out, n, E);
}

// Round 18
// 184.300 us; speedup vs baseline: 3.2785x; 1.0100x over previous
//
#include <hip/hip_runtime.h>

// ---------------------------------------------------------------------------
// GCN pipeline, round 18 (round-17 structure; LDS Hillis-Steele scans ->
// wave-shfl scans, 16+ barriers/scan -> 2):
//   histA -> scanTiles -> multisplit2 -> place_fine2 -> agg1_t12 (fused
//   5-dim gather + W1/relu/W2) -> agg2_fc (layer-2 aggregate + FC head).
// Round-17 win confirmed the fusion-granularity rule (3125 blocks, ~8/CU).
// agg2_fc is at its per-XCD first-touch fetch floor (~83MB); remaining
// overhead attacked here: barrier-heavy scans in the CSR-build chain.
// ---------------------------------------------------------------------------

#define MS_TILE 2048
#define MAXB 512  // padded coarse-bucket count (NBkt = ceil(n/256) <= 512)
#define AGG_NODES 32
#define AGG_STAGE 1024

// Inclusive shfl scan across the wave; then cross-wave combine via wsum[4].
// Caller must __syncthreads() between the wsum write here and any wsum reuse.
__device__ inline int scan256_incl(int v, int lane, int w, int* wsum,
                                   int* total) {
    int incl = v;
#pragma unroll
    for (int d = 1; d < 64; d <<= 1) {
        int up = __shfl_up(incl, d, 64);
        if (lane >= d) incl += up;
    }
    if (lane == 63) wsum[w] = incl;
    __syncthreads();
    int add = 0;
    if (w > 0) add += wsum[0];
    if (w > 1) add += wsum[1];
    if (w > 2) add += wsum[2];
    *total = wsum[0] + wsum[1] + wsum[2] + wsum[3];
    return incl + add;
}

// per-tile LDS histogram of dst>>8 -> histG[tile*512 + b] (coalesced rows)
__global__ __launch_bounds__(256) void histA(const int* __restrict__ dst,
                                             int* __restrict__ histG, int E) {
    __shared__ int h[MAXB];
    int t = threadIdx.x;
    h[t] = 0;
    h[t + 256] = 0;
    __syncthreads();
    int base = blockIdx.x * MS_TILE;
    int cnt = min(MS_TILE, E - base);
    for (int k = t; k < cnt; k += 256) atomicAdd(&h[dst[base + k] >> 8], 1);
    __syncthreads();
    histG[blockIdx.x * MAXB + t] = h[t];
    histG[blockIdx.x * MAXB + 256 + t] = h[t + 256];
}

// one block per bucket b: exclusive scan of histG[.][b] across tiles ->
// offsG[tile*512+b]; bucket total -> bucketTotal[b]
__global__ __launch_bounds__(256) void scanTiles(const int* __restrict__ histG,
                                                 int* __restrict__ offsG,
                                                 int* __restrict__ bucketTotal,
                                                 int nTiles) {
    __shared__ int wsum[4];
    int b = blockIdx.x, t = threadIdx.x;
    int lane = t & 63, w = t >> 6;
    int run = 0;
    for (int base = 0; base < nTiles; base += 256) {
        int idx = base + t;
        int v = (idx < nTiles) ? histG[idx * MAXB + b] : 0;
        int total;
        int incl = scan256_incl(v, lane, w, wsum, &total);
        if (idx < nTiles) offsG[idx * MAXB + b] = incl - v + run;
        run += total;
        __syncthreads();  // protect wsum before next chunk
    }
    if (t == 0) bucketTotal[b] = run;
}

// Deterministic tile counting-sort. Payload: (src<<8)|(dst&255).
// Also scans bucketTotal -> global bucket bases; tile 0 publishes gbase.
__global__ __launch_bounds__(256) void multisplit2(
    const int* __restrict__ src, const int* __restrict__ dst,
    const int* __restrict__ histG, const int* __restrict__ offsG,
    const int* __restrict__ btot, int* __restrict__ gbaseOut,
    unsigned* __restrict__ binned, int E) {
    __shared__ unsigned stage[MS_TILE];
    __shared__ unsigned short sb[MS_TILE];
    __shared__ int hoff[MAXB + 1];
    __shared__ int hcur[MAXB];
    __shared__ int gb[MAXB];
    __shared__ int wsum[4];
    int t = threadIdx.x;
    int lane = t & 63, w = t >> 6;
    int tile = blockIdx.x;
    int base = tile * MS_TILE;
    int cnt = min(MS_TILE, E - base);

    // scan 1: bucket totals -> global bucket bases (2 elems/thread)
    int b0 = btot[2 * t], b1v = btot[2 * t + 1];
    int s2 = b0 + b1v;
    int tot2;
    int incl2 = scan256_incl(s2, lane, w, wsum, &tot2);
    int ex2 = incl2 - s2;
    gb[2 * t] = ex2 + offsG[tile * MAXB + 2 * t];
    gb[2 * t + 1] = ex2 + b0 + offsG[tile * MAXB + 2 * t + 1];
    if (tile == 0) {
        gbaseOut[2 * t] = ex2;
        gbaseOut[2 * t + 1] = ex2 + b0;
        if (t == 255) gbaseOut[MAXB] = E;
    }
    __syncthreads();  // protect wsum before scan 2

    // scan 2: per-tile hist -> LDS stage layout
    int a0 = histG[tile * MAXB + 2 * t];
    int a1 = histG[tile * MAXB + 2 * t + 1];
    int s = a0 + a1;
    int tot;
    int incl = scan256_incl(s, lane, w, wsum, &tot);
    int ex = incl - s;
    hoff[2 * t] = ex;
    hoff[2 * t + 1] = ex + a0;
    hcur[2 * t] = ex;
    hcur[2 * t + 1] = ex + a0;
    if (t == 255) hoff[MAXB] = cnt;
    __syncthreads();
    for (int k = t; k < cnt; k += 256) {
        int d = dst[base + k];
        int b = d >> 8;
        int p = atomicAdd(&hcur[b], 1);
        stage[p] = ((unsigned)src[base + k] << 8) | (unsigned)(d & 255);
        sb[p] = (unsigned short)b;
    }
    __syncthreads();
    for (int k = t; k < cnt; k += 256) {
        int b = sb[k];
        binned[gb[b] + (k - hoff[b])] = stage[k];
    }
}

// Per coarse bucket: per-node deg via LDS count, shfl scan -> offs, dinv,
// y[i,:] = dinv[i]*x[i,:] (padded to 8 floats), then exact CSR scatter.
__global__ __launch_bounds__(256) void place_fine2(
    const unsigned* __restrict__ binned, const int* __restrict__ gbase,
    const float* __restrict__ x, int* __restrict__ offs,
    float* __restrict__ dinv, float* __restrict__ y, int* __restrict__ srcs, int n) {
    __shared__ int cnt[256];
    __shared__ int lcur[256];
    __shared__ int wsum[4];
    int t = threadIdx.x, b = blockIdx.x;
    int lane = t & 63, w = t >> 6;
    int node0 = b << 8;
    int nn = min(256, n - node0);
    int e0 = gbase[b], e1 = gbase[b + 1];
    cnt[t] = 0;
    __syncthreads();
    for (int k = e0 + t; k < e1; k += 256) atomicAdd(&cnt[binned[k] & 255u], 1);
    __syncthreads();
    int c = cnt[t];
    int tot;
    int incl = scan256_incl(c, lane, w, wsum, &tot);
    int myoff = e0 + (incl - c);
    lcur[t] = myoff;
    if (t < nn) {
        int node = node0 + t;
        offs[node] = myoff;
        float di = 1.0f / sqrtf((float)(c + 1));  // +1 self loop
        dinv[node] = di;
        const float* xr = x + (size_t)node * 5;
        float4 a = {xr[0] * di, xr[1] * di, xr[2] * di, xr[3] * di};
        float4 bq = {xr[4] * di, 0.f, 0.f, 0.f};
        *(float4*)(y + (size_t)node * 8) = a;
        *(float4*)(y + (size_t)node * 8 + 4) = bq;
    }
    __syncthreads();
    for (int k = e0 + t; k < e1; k += 256) {
        unsigned wd = binned[k];
        int p = atomicAdd(&lcur[wd & 255u], 1);
        srcs[p] = (int)(wd >> 8);
    }
}

// FUSED layer-1 aggregate + both transforms, at 32-node granularity
// (3125 blocks, ~8 blocks/CU). Gather: 8 threads/node, ~2 edges each,
// shfl-xor reduce within the in-wave 8-lane group; z lives only in LDS
// (zs stride 6, slot 5 = dinv). Then o1 = relu(z@W1+b1), h2 = dinv*(o1@W2).
__global__ __launch_bounds__(256) void agg1_t12(
    const float* __restrict__ y, const int* __restrict__ srcs,
    const int* __restrict__ offs, const float* __restrict__ dinv,
    const float* __restrict__ W1, const float* __restrict__ b1,
    const float* __restrict__ W2, float* __restrict__ h2, int n, int E) {
    __shared__ float w1s[320];
    __shared__ float b1s[64];
    __shared__ float w2s[64 * 32];
    __shared__ float o1[32 * 64];
    __shared__ float zs[32 * 6];
    int t = threadIdx.x;
    w1s[t] = W1[t];
    if (t < 64) {
        w1s[t + 256] = W1[t + 256];
        b1s[t] = b1[t];
    }
#pragma unroll
    for (int r = 0; r < 8; ++r) w2s[r * 256 + t] = W2[r * 256 + t];

    int node0 = blockIdx.x * 32;
    int li = t >> 3, e = t & 7;  // node-in-block, edge-lane
    int i = node0 + li;
    const float4* yv = (const float4*)y;
    float4 a = {0.f, 0.f, 0.f, 0.f};
    float b0 = 0.f;
    if (i < n) {
        int off = offs[i];
        int cnt = ((i + 1 < n) ? offs[i + 1] : E) - off;
        if (e == 0) {  // self-loop term once per node
            a = yv[(size_t)i * 2];
            b0 = y[(size_t)i * 8 + 4];
        }
        for (int p = e; p < cnt; p += 8) {
            int s = srcs[off + p];
            float4 v = yv[(size_t)s * 2];
            float w = y[(size_t)s * 8 + 4];
            a.x += v.x; a.y += v.y; a.z += v.z; a.w += v.w;
            b0 += w;
        }
    }
    // reduce the 8-lane group (lanes t..t|7 are in one wave, one node)
#pragma unroll
    for (int m = 4; m >= 1; m >>= 1) {
        a.x += __shfl_xor(a.x, m, 64);
        a.y += __shfl_xor(a.y, m, 64);
        a.z += __shfl_xor(a.z, m, 64);
        a.w += __shfl_xor(a.w, m, 64);
        b0  += __shfl_xor(b0, m, 64);
    }
    if (i < n && e == 0) {
        float di = dinv[i];
        zs[li * 6 + 0] = a.x * di;
        zs[li * 6 + 1] = a.y * di;
        zs[li * 6 + 2] = a.z * di;
        zs[li * 6 + 3] = a.w * di;
        zs[li * 6 + 4] = b0 * di;
        zs[li * 6 + 5] = di;
    }
    __syncthreads();  // zs + weights visible
    // o1 = relu(z@W1 + b1): 32 nodes x 64 feats
#pragma unroll
    for (int r = 0; r < 8; ++r) {
        int idx = r * 256 + t;
        int lj = idx >> 6, f = idx & 63;
        if (node0 + lj < n) {
            const float* zr = zs + lj * 6;
            float acc = b1s[f];
#pragma unroll
            for (int k = 0; k < 5; ++k) acc += zr[k] * w1s[k * 64 + f];
            o1[lj * 64 + f] = fmaxf(acc, 0.0f);
        }
    }
    __syncthreads();
    // h2 = dinv*(o1@W2): 32 nodes x 32 feats
#pragma unroll
    for (int r = 0; r < 4; ++r) {
        int idx = r * 256 + t;
        int lj = idx >> 5, g = idx & 31;
        int i2 = node0 + lj;
        if (i2 < n) {
            float acc = 0.f;
#pragma unroll
            for (int k = 0; k < 64; ++k) acc += o1[lj * 64 + k] * w2s[k * 32 + g];
            h2[(size_t)i2 * 32 + g] = acc * zs[lj * 6 + 5];
        }
    }
}

// FUSED layer-2 aggregate + FC head (round-12 measured best). Block = 32
// nodes x 8 f4-groups; LDS-staged CSR indices, 8-deep float4 gather unroll.
__global__ __launch_bounds__(256) void agg2_fc(
    const float* __restrict__ h, const int* __restrict__ srcs,
    const int* __restrict__ offs, const float* __restrict__ dinv,
    const float* __restrict__ b2, const float* __restrict__ fcW1,
    const float* __restrict__ fcb1, const float* __restrict__ fcW2,
    const float* __restrict__ fcb2, float* __restrict__ out, int n, int E) {
    __shared__ int sidx[AGG_STAGE];
    __shared__ float sm[AGG_NODES * 33];  // out2, stride-33 padded
    __shared__ float x3s[AGG_NODES * 16];
    __shared__ float w1s[512];
    __shared__ float w2s[32];
    __shared__ float b1s[16];
    __shared__ float b2s[2];
    __shared__ float bs2[32];
    int t = threadIdx.x;
    w1s[t] = fcW1[t];
    w1s[t + 256] = fcW1[t + 256];
    if (t < 32) { w2s[t] = fcW2[t]; bs2[t] = b2[t]; }
    if (t < 16) b1s[t] = fcb1[t];
    if (t < 2) b2s[t] = fcb2[t];

    int node0 = blockIdx.x * AGG_NODES;
    int li = t >> 3, fq = t & 7;  // node-in-block, 4-feature group
    int i = node0 + li;
    bool live = (i < n);
    const char* hb = (const char*)h;

    int e0 = offs[node0];
    int eEnd = (node0 + AGG_NODES < n) ? offs[node0 + AGG_NODES] : E;
    int myOff = 0, myCnt = 0;
    float4 acc = {0.f, 0.f, 0.f, 0.f};
    if (live) {
        myOff = offs[i];
        myCnt = ((i + 1 < n) ? offs[i + 1] : E) - myOff;
        acc = *(const float4*)(hb + ((size_t)i << 7) + (fq << 4));  // self-loop
    }

    for (int cs = e0; cs < eEnd; cs += AGG_STAGE) {
        int ce = min(cs + AGG_STAGE, eEnd);
        for (int k = cs + t; k < ce; k += 256) sidx[k - cs] = srcs[k] << 7;
        __syncthreads();
        int ps = max(myOff, cs), pe = min(myOff + myCnt, ce);
        int p = ps;
        for (; p + 8 <= pe; p += 8) {
            int o[8];
#pragma unroll
            for (int u = 0; u < 8; ++u) o[u] = sidx[p + u - cs];
            float4 v[8];
#pragma unroll
            for (int u = 0; u < 8; ++u)
                v[u] = *(const float4*)(hb + o[u] + (fq << 4));
#pragma unroll
            for (int u = 0; u < 8; ++u) {
                acc.x += v[u].x; acc.y += v[u].y;
                acc.z += v[u].z; acc.w += v[u].w;
            }
        }
        for (; p + 4 <= pe; p += 4) {
            int o0 = sidx[p - cs], o1 = sidx[p + 1 - cs];
            int o2 = sidx[p + 2 - cs], o3 = sidx[p + 3 - cs];
            float4 v0 = *(const float4*)(hb + o0 + (fq << 4));
            float4 v1 = *(const float4*)(hb + o1 + (fq << 4));
            float4 v2 = *(const float4*)(hb + o2 + (fq << 4));
            float4 v3 = *(const float4*)(hb + o3 + (fq << 4));
            acc.x += (v0.x + v1.x) + (v2.x + v3.x);
            acc.y += (v0.y + v1.y) + (v2.y + v3.y);
            acc.z += (v0.z + v1.z) + (v2.z + v3.z);
            acc.w += (v0.w + v1.w) + (v2.w + v3.w);
        }
        for (; p < pe; ++p) {
            float4 v = *(const float4*)(hb + sidx[p - cs] + (fq << 4));
            acc.x += v.x; acc.y += v.y; acc.z += v.z; acc.w += v.w;
        }
        __syncthreads();
    }

    if (live) {
        float di = dinv[i];
        int f0 = fq << 2;
        sm[li * 33 + f0 + 0] = fmaxf(di * acc.x + bs2[f0 + 0], 0.f);
        sm[li * 33 + f0 + 1] = fmaxf(di * acc.y + bs2[f0 + 1], 0.f);
        sm[li * 33 + f0 + 2] = fmaxf(di * acc.z + bs2[f0 + 2], 0.f);
        sm[li * 33 + f0 + 3] = fmaxf(di * acc.w + bs2[f0 + 3], 0.f);
    }
    __syncthreads();
#pragma unroll
    for (int r = 0; r < 2; ++r) {
        int idx = r * 256 + t;
        int lj = idx >> 4, j = idx & 15;
        if (node0 + lj < n) {
            float a = b1s[j];
#pragma unroll
            for (int k = 0; k < 32; ++k) a += sm[lj * 33 + k] * w1s[k * 16 + j];
            x3s[lj * 16 + j] = fmaxf(a, 0.f);
        }
    }
    __syncthreads();
    if (t < 64) {
        int lj = t >> 1, o = t & 1;
        if (node0 + lj < n) {
            float a = b2s[o];
#pragma unroll
            for (int j = 0; j < 16; ++j) a += x3s[lj * 16 + j] * w2s[j * 2 + o];
            out[(size_t)(node0 + lj) * 2 + o] = a;
        }
    }
}

extern "C" void kernel_launch(void* const* d_in, const int* in_sizes, int n_in,
                              void* d_out, int out_size, void* d_ws, size_t ws_size,
                              hipStream_t stream) {
    const float* edge_attr = (const float*)d_in[0];
    const int* edge_index  = (const int*)d_in[1];
    const float* W1   = (const float*)d_in[2];
    const float* b1   = (const float*)d_in[3];
    const float* W2   = (const float*)d_in[4];
    const float* b2   = (const float*)d_in[5];
    const float* fcW1 = (const float*)d_in[6];
    const float* fcb1 = (const float*)d_in[7];
    const float* fcW2 = (const float*)d_in[8];
    const float* fcb2 = (const float*)d_in[9];
    float* out = (float*)d_out;

    int n = in_sizes[0] / 5;
    int E = in_sizes[1] / 2;
    int NBkt = (n + 255) >> 8;                 // 391 for n=100000 (<= MAXB)
    int nTiles = (E + MS_TILE - 1) / MS_TILE;  // 782
    const int* src = edge_index;
    const int* dst = edge_index + E;

    char* ws = (char*)d_ws;
    auto alloc = [&](size_t bytes) {
        char* p = ws;
        ws += (bytes + 255) & ~(size_t)255;
        return p;
    };
    int*      offs   = (int*)alloc((size_t)n * 4);
    float*    dinv   = (float*)alloc((size_t)n * 4);
    int*      histG  = (int*)alloc((size_t)nTiles * MAXB * 4);
    int*      offsG  = (int*)alloc((size_t)nTiles * MAXB * 4);
    int*      btot   = (int*)alloc((size_t)MAXB * 4);
    int*      gbase  = (int*)alloc((size_t)(MAXB + 1) * 4);
    int*      srcs   = (int*)alloc((size_t)E * 4);
    unsigned* binned = (unsigned*)alloc((size_t)E * 4);
    float*    y      = (float*)alloc((size_t)n * 8 * 4);
    float*    h2     = (float*)alloc((size_t)n * 32 * 4);

    histA<<<nTiles, 256, 0, stream>>>(dst, histG, E);
    scanTiles<<<MAXB, 256, 0, stream>>>(histG, offsG, btot, nTiles);
    multisplit2<<<nTiles, 256, 0, stream>>>(src, dst, histG, offsG, btot, gbase,
                                            binned, E);
    place_fine2<<<NBkt, 256, 0, stream>>>(binned, gbase, edge_attr, offs, dinv,
                                          y, srcs, n);
    agg1_t12<<<(n + 31) / 32, 256, 0, stream>>>(y, srcs, offs, dinv, W1, b1, W2,
                                                h2, n, E);
    agg2_fc<<<(n + AGG_NODES - 1) / AGG_NODES, 256, 0, stream>>>(
        h2, srcs, offs, dinv, b2, fcW1, fcb1, fcW2, fcb2, out, n, E);
}

// Round 19
// 179.073 us; speedup vs baseline: 3.3742x; 1.0292x over previous
//
#include <hip/hip_runtime.h>

// ---------------------------------------------------------------------------
// GCN pipeline, round 19 (round-18 structure; h2 stored as fp16):
//   histA -> scanTiles -> multisplit2 -> place_fine2 -> agg1_t12 (fused
//   5-dim gather + W1/relu/W2, h2 out in fp16) -> agg2_fc (fp16 h2 gathers,
//   fp32 accumulate, FC head).
// Round-18 accounting: agg2_fc (~33us) is random-access bound — 83MB of
// L2-miss traffic since 12.8MB h2 > 4MB per-XCD L2. fp16 h2 halves the
// table (6.4MB): less miss traffic + higher hit rate. Accumulation stays
// fp32; predicted absmax ~1-2e-4 vs 3.78e-4 threshold.
// ---------------------------------------------------------------------------

#define MS_TILE 2048
#define MAXB 512  // padded coarse-bucket count (NBkt = ceil(n/256) <= 512)
#define AGG_NODES 32
#define AGG_STAGE 1024

typedef __attribute__((ext_vector_type(4))) _Float16 half4;

// Inclusive shfl scan across the wave; then cross-wave combine via wsum[4].
__device__ inline int scan256_incl(int v, int lane, int w, int* wsum,
                                   int* total) {
    int incl = v;
#pragma unroll
    for (int d = 1; d < 64; d <<= 1) {
        int up = __shfl_up(incl, d, 64);
        if (lane >= d) incl += up;
    }
    if (lane == 63) wsum[w] = incl;
    __syncthreads();
    int add = 0;
    if (w > 0) add += wsum[0];
    if (w > 1) add += wsum[1];
    if (w > 2) add += wsum[2];
    *total = wsum[0] + wsum[1] + wsum[2] + wsum[3];
    return incl + add;
}

// per-tile LDS histogram of dst>>8 -> histG[tile*512 + b] (coalesced rows)
__global__ __launch_bounds__(256) void histA(const int* __restrict__ dst,
                                             int* __restrict__ histG, int E) {
    __shared__ int h[MAXB];
    int t = threadIdx.x;
    h[t] = 0;
    h[t + 256] = 0;
    __syncthreads();
    int base = blockIdx.x * MS_TILE;
    int cnt = min(MS_TILE, E - base);
    for (int k = t; k < cnt; k += 256) atomicAdd(&h[dst[base + k] >> 8], 1);
    __syncthreads();
    histG[blockIdx.x * MAXB + t] = h[t];
    histG[blockIdx.x * MAXB + 256 + t] = h[t + 256];
}

// one block per bucket b: exclusive scan of histG[.][b] across tiles
__global__ __launch_bounds__(256) void scanTiles(const int* __restrict__ histG,
                                                 int* __restrict__ offsG,
                                                 int* __restrict__ bucketTotal,
                                                 int nTiles) {
    __shared__ int wsum[4];
    int b = blockIdx.x, t = threadIdx.x;
    int lane = t & 63, w = t >> 6;
    int run = 0;
    for (int base = 0; base < nTiles; base += 256) {
        int idx = base + t;
        int v = (idx < nTiles) ? histG[idx * MAXB + b] : 0;
        int total;
        int incl = scan256_incl(v, lane, w, wsum, &total);
        if (idx < nTiles) offsG[idx * MAXB + b] = incl - v + run;
        run += total;
        __syncthreads();
    }
    if (t == 0) bucketTotal[b] = run;
}

// Deterministic tile counting-sort. Payload: (src<<8)|(dst&255).
__global__ __launch_bounds__(256) void multisplit2(
    const int* __restrict__ src, const int* __restrict__ dst,
    const int* __restrict__ histG, const int* __restrict__ offsG,
    const int* __restrict__ btot, int* __restrict__ gbaseOut,
    unsigned* __restrict__ binned, int E) {
    __shared__ unsigned stage[MS_TILE];
    __shared__ unsigned short sb[MS_TILE];
    __shared__ int hoff[MAXB + 1];
    __shared__ int hcur[MAXB];
    __shared__ int gb[MAXB];
    __shared__ int wsum[4];
    int t = threadIdx.x;
    int lane = t & 63, w = t >> 6;
    int tile = blockIdx.x;
    int base = tile * MS_TILE;
    int cnt = min(MS_TILE, E - base);

    int b0 = btot[2 * t], b1v = btot[2 * t + 1];
    int s2 = b0 + b1v;
    int tot2;
    int incl2 = scan256_incl(s2, lane, w, wsum, &tot2);
    int ex2 = incl2 - s2;
    gb[2 * t] = ex2 + offsG[tile * MAXB + 2 * t];
    gb[2 * t + 1] = ex2 + b0 + offsG[tile * MAXB + 2 * t + 1];
    if (tile == 0) {
        gbaseOut[2 * t] = ex2;
        gbaseOut[2 * t + 1] = ex2 + b0;
        if (t == 255) gbaseOut[MAXB] = E;
    }
    __syncthreads();

    int a0 = histG[tile * MAXB + 2 * t];
    int a1 = histG[tile * MAXB + 2 * t + 1];
    int s = a0 + a1;
    int tot;
    int incl = scan256_incl(s, lane, w, wsum, &tot);
    int ex = incl - s;
    hoff[2 * t] = ex;
    hoff[2 * t + 1] = ex + a0;
    hcur[2 * t] = ex;
    hcur[2 * t + 1] = ex + a0;
    if (t == 255) hoff[MAXB] = cnt;
    __syncthreads();
    for (int k = t; k < cnt; k += 256) {
        int d = dst[base + k];
        int b = d >> 8;
        int p = atomicAdd(&hcur[b], 1);
        stage[p] = ((unsigned)src[base + k] << 8) | (unsigned)(d & 255);
        sb[p] = (unsigned short)b;
    }
    __syncthreads();
    for (int k = t; k < cnt; k += 256) {
        int b = sb[k];
        binned[gb[b] + (k - hoff[b])] = stage[k];
    }
}

// Per coarse bucket: per-node deg via LDS count, shfl scan -> offs, dinv,
// y[i,:] = dinv[i]*x[i,:] (padded to 8 floats), then exact CSR scatter.
__global__ __launch_bounds__(256) void place_fine2(
    const unsigned* __restrict__ binned, const int* __restrict__ gbase,
    const float* __restrict__ x, int* __restrict__ offs,
    float* __restrict__ dinv, float* __restrict__ y, int* __restrict__ srcs, int n) {
    __shared__ int cnt[256];
    __shared__ int lcur[256];
    __shared__ int wsum[4];
    int t = threadIdx.x, b = blockIdx.x;
    int lane = t & 63, w = t >> 6;
    int node0 = b << 8;
    int nn = min(256, n - node0);
    int e0 = gbase[b], e1 = gbase[b + 1];
    cnt[t] = 0;
    __syncthreads();
    for (int k = e0 + t; k < e1; k += 256) atomicAdd(&cnt[binned[k] & 255u], 1);
    __syncthreads();
    int c = cnt[t];
    int tot;
    int incl = scan256_incl(c, lane, w, wsum, &tot);
    int myoff = e0 + (incl - c);
    lcur[t] = myoff;
    if (t < nn) {
        int node = node0 + t;
        offs[node] = myoff;
        float di = 1.0f / sqrtf((float)(c + 1));  // +1 self loop
        dinv[node] = di;
        const float* xr = x + (size_t)node * 5;
        float4 a = {xr[0] * di, xr[1] * di, xr[2] * di, xr[3] * di};
        float4 bq = {xr[4] * di, 0.f, 0.f, 0.f};
        *(float4*)(y + (size_t)node * 8) = a;
        *(float4*)(y + (size_t)node * 8 + 4) = bq;
    }
    __syncthreads();
    for (int k = e0 + t; k < e1; k += 256) {
        unsigned wd = binned[k];
        int p = atomicAdd(&lcur[wd & 255u], 1);
        srcs[p] = (int)(wd >> 8);
    }
}

// FUSED layer-1 aggregate + both transforms, 32-node blocks (3125 blocks).
// Gather: 8 threads/node, shfl-xor reduce; z in LDS. h2 written as fp16.
__global__ __launch_bounds__(256) void agg1_t12(
    const float* __restrict__ y, const int* __restrict__ srcs,
    const int* __restrict__ offs, const float* __restrict__ dinv,
    const float* __restrict__ W1, const float* __restrict__ b1,
    const float* __restrict__ W2, _Float16* __restrict__ h2, int n, int E) {
    __shared__ float w1s[320];
    __shared__ float b1s[64];
    __shared__ float w2s[64 * 32];
    __shared__ float o1[32 * 64];
    __shared__ float zs[32 * 6];
    int t = threadIdx.x;
    w1s[t] = W1[t];
    if (t < 64) {
        w1s[t + 256] = W1[t + 256];
        b1s[t] = b1[t];
    }
#pragma unroll
    for (int r = 0; r < 8; ++r) w2s[r * 256 + t] = W2[r * 256 + t];

    int node0 = blockIdx.x * 32;
    int li = t >> 3, e = t & 7;
    int i = node0 + li;
    const float4* yv = (const float4*)y;
    float4 a = {0.f, 0.f, 0.f, 0.f};
    float b0 = 0.f;
    if (i < n) {
        int off = offs[i];
        int cnt = ((i + 1 < n) ? offs[i + 1] : E) - off;
        if (e == 0) {
            a = yv[(size_t)i * 2];
            b0 = y[(size_t)i * 8 + 4];
        }
        for (int p = e; p < cnt; p += 8) {
            int s = srcs[off + p];
            float4 v = yv[(size_t)s * 2];
            float w = y[(size_t)s * 8 + 4];
            a.x += v.x; a.y += v.y; a.z += v.z; a.w += v.w;
            b0 += w;
        }
    }
#pragma unroll
    for (int m = 4; m >= 1; m >>= 1) {
        a.x += __shfl_xor(a.x, m, 64);
        a.y += __shfl_xor(a.y, m, 64);
        a.z += __shfl_xor(a.z, m, 64);
        a.w += __shfl_xor(a.w, m, 64);
        b0  += __shfl_xor(b0, m, 64);
    }
    if (i < n && e == 0) {
        float di = dinv[i];
        zs[li * 6 + 0] = a.x * di;
        zs[li * 6 + 1] = a.y * di;
        zs[li * 6 + 2] = a.z * di;
        zs[li * 6 + 3] = a.w * di;
        zs[li * 6 + 4] = b0 * di;
        zs[li * 6 + 5] = di;
    }
    __syncthreads();
#pragma unroll
    for (int r = 0; r < 8; ++r) {
        int idx = r * 256 + t;
        int lj = idx >> 6, f = idx & 63;
        if (node0 + lj < n) {
            const float* zr = zs + lj * 6;
            float acc = b1s[f];
#pragma unroll
            for (int k = 0; k < 5; ++k) acc += zr[k] * w1s[k * 64 + f];
            o1[lj * 64 + f] = fmaxf(acc, 0.0f);
        }
    }
    __syncthreads();
#pragma unroll
    for (int r = 0; r < 4; ++r) {
        int idx = r * 256 + t;
        int lj = idx >> 5, g = idx & 31;
        int i2 = node0 + lj;
        if (i2 < n) {
            float acc = 0.f;
#pragma unroll
            for (int k = 0; k < 64; ++k) acc += o1[lj * 64 + k] * w2s[k * 32 + g];
            h2[(size_t)i2 * 32 + g] = (_Float16)(acc * zs[lj * 6 + 5]);
        }
    }
}

// FUSED layer-2 aggregate + FC head. fp16 h2 rows (64B), 8 threads/node
// each gathering 8B (half4); fp32 accumulation; LDS-staged CSR indices.
__global__ __launch_bounds__(256) void agg2_fc(
    const _Float16* __restrict__ h, const int* __restrict__ srcs,
    const int* __restrict__ offs, const float* __restrict__ dinv,
    const float* __restrict__ b2, const float* __restrict__ fcW1,
    const float* __restrict__ fcb1, const float* __restrict__ fcW2,
    const float* __restrict__ fcb2, float* __restrict__ out, int n, int E) {
    __shared__ int sidx[AGG_STAGE];
    __shared__ float sm[AGG_NODES * 33];
    __shared__ float x3s[AGG_NODES * 16];
    __shared__ float w1s[512];
    __shared__ float w2s[32];
    __shared__ float b1s[16];
    __shared__ float b2s[2];
    __shared__ float bs2[32];
    int t = threadIdx.x;
    w1s[t] = fcW1[t];
    w1s[t + 256] = fcW1[t + 256];
    if (t < 32) { w2s[t] = fcW2[t]; bs2[t] = b2[t]; }
    if (t < 16) b1s[t] = fcb1[t];
    if (t < 2) b2s[t] = fcb2[t];

    int node0 = blockIdx.x * AGG_NODES;
    int li = t >> 3, fq = t & 7;
    int i = node0 + li;
    bool live = (i < n);
    const char* hb = (const char*)h;

    int e0 = offs[node0];
    int eEnd = (node0 + AGG_NODES < n) ? offs[node0 + AGG_NODES] : E;
    int myOff = 0, myCnt = 0;
    float4 acc = {0.f, 0.f, 0.f, 0.f};
    if (live) {
        myOff = offs[i];
        myCnt = ((i + 1 < n) ? offs[i + 1] : E) - myOff;
        half4 sv = *(const half4*)(hb + ((size_t)i << 6) + (fq << 3));
        acc.x = (float)sv.x; acc.y = (float)sv.y;
        acc.z = (float)sv.z; acc.w = (float)sv.w;
    }

    for (int cs = e0; cs < eEnd; cs += AGG_STAGE) {
        int ce = min(cs + AGG_STAGE, eEnd);
        for (int k = cs + t; k < ce; k += 256) sidx[k - cs] = srcs[k] << 6;
        __syncthreads();
        int ps = max(myOff, cs), pe = min(myOff + myCnt, ce);
        int p = ps;
        for (; p + 8 <= pe; p += 8) {
            int o[8];
#pragma unroll
            for (int u = 0; u < 8; ++u) o[u] = sidx[p + u - cs];
            half4 v[8];
#pragma unroll
            for (int u = 0; u < 8; ++u)
                v[u] = *(const half4*)(hb + o[u] + (fq << 3));
#pragma unroll
            for (int u = 0; u < 8; ++u) {
                acc.x += (float)v[u].x; acc.y += (float)v[u].y;
                acc.z += (float)v[u].z; acc.w += (float)v[u].w;
            }
        }
        for (; p + 4 <= pe; p += 4) {
            int o0 = sidx[p - cs], o1 = sidx[p + 1 - cs];
            int o2 = sidx[p + 2 - cs], o3 = sidx[p + 3 - cs];
            half4 v0 = *(const half4*)(hb + o0 + (fq << 3));
            half4 v1 = *(const half4*)(hb + o1 + (fq << 3));
            half4 v2 = *(const half4*)(hb + o2 + (fq << 3));
            half4 v3 = *(const half4*)(hb + o3 + (fq << 3));
            acc.x += (float)v0.x + (float)v1.x + (float)v2.x + (float)v3.x;
            acc.y += (float)v0.y + (float)v1.y + (float)v2.y + (float)v3.y;
            acc.z += (float)v0.z + (float)v1.z + (float)v2.z + (float)v3.z;
            acc.w += (float)v0.w + (float)v1.w + (float)v2.w + (float)v3.w;
        }
        for (; p < pe; ++p) {
            half4 v = *(const half4*)(hb + sidx[p - cs] + (fq << 3));
            acc.x += (float)v.x; acc.y += (float)v.y;
            acc.z += (float)v.z; acc.w += (float)v.w;
        }
        __syncthreads();
    }

    if (live) {
        float di = dinv[i];
        int f0 = fq << 2;
        sm[li * 33 + f0 + 0] = fmaxf(di * acc.x + bs2[f0 + 0], 0.f);
        sm[li * 33 + f0 + 1] = fmaxf(di * acc.y + bs2[f0 + 1], 0.f);
        sm[li * 33 + f0 + 2] = fmaxf(di * acc.z + bs2[f0 + 2], 0.f);
        sm[li * 33 + f0 + 3] = fmaxf(di * acc.w + bs2[f0 + 3], 0.f);
    }
    __syncthreads();
#pragma unroll
    for (int r = 0; r < 2; ++r) {
        int idx = r * 256 + t;
        int lj = idx >> 4, j = idx & 15;
        if (node0 + lj < n) {
            float a = b1s[j];
#pragma unroll
            for (int k = 0; k < 32; ++k) a += sm[lj * 33 + k] * w1s[k * 16 + j];
            x3s[lj * 16 + j] = fmaxf(a, 0.f);
        }
    }
    __syncthreads();
    if (t < 64) {
        int lj = t >> 1, o = t & 1;
        if (node0 + lj < n) {
            float a = b2s[o];
#pragma unroll
            for (int j = 0; j < 16; ++j) a += x3s[lj * 16 + j] * w2s[j * 2 + o];
            out[(size_t)(node0 + lj) * 2 + o] = a;
        }
    }
}

extern "C" void kernel_launch(void* const* d_in, const int* in_sizes, int n_in,
                              void* d_out, int out_size, void* d_ws, size_t ws_size,
                              hipStream_t stream) {
    const float* edge_attr = (const float*)d_in[0];
    const int* edge_index  = (const int*)d_in[1];
    const float* W1   = (const float*)d_in[2];
    const float* b1   = (const float*)d_in[3];
    const float* W2   = (const float*)d_in[4];
    const float* b2   = (const float*)d_in[5];
    const float* fcW1 = (const float*)d_in[6];
    const float* fcb1 = (const float*)d_in[7];
    const float* fcW2 = (const float*)d_in[8];
    const float* fcb2 = (const float*)d_in[9];
    float* out = (float*)d_out;

    int n = in_sizes[0] / 5;
    int E = in_sizes[1] / 2;
    int NBkt = (n + 255) >> 8;                 // 391 for n=100000 (<= MAXB)
    int nTiles = (E + MS_TILE - 1) / MS_TILE;  // 782
    const int* src = edge_index;
    const int* dst = edge_index + E;

    char* ws = (char*)d_ws;
    auto alloc = [&](size_t bytes) {
        char* p = ws;
        ws += (bytes + 255) & ~(size_t)255;
        return p;
    };
    int*      offs   = (int*)alloc((size_t)n * 4);
    float*    dinv   = (float*)alloc((size_t)n * 4);
    int*      histG  = (int*)alloc((size_t)nTiles * MAXB * 4);
    int*      offsG  = (int*)alloc((size_t)nTiles * MAXB * 4);
    int*      btot   = (int*)alloc((size_t)MAXB * 4);
    int*      gbase  = (int*)alloc((size_t)(MAXB + 1) * 4);
    int*      srcs   = (int*)alloc((size_t)E * 4);
    unsigned* binned = (unsigned*)alloc((size_t)E * 4);
    float*    y      = (float*)alloc((size_t)n * 8 * 4);
    _Float16* h2     = (_Float16*)alloc((size_t)n * 32 * 2);

    histA<<<nTiles, 256, 0, stream>>>(dst, histG, E);
    scanTiles<<<MAXB, 256, 0, stream>>>(histG, offsG, btot, nTiles);
    multisplit2<<<nTiles, 256, 0, stream>>>(src, dst, histG, offsG, btot, gbase,
                                            binned, E);
    place_fine2<<<NBkt, 256, 0, stream>>>(binned, gbase, edge_attr, offs, dinv,
                                          y, srcs, n);
    agg1_t12<<<(n + 31) / 32, 256, 0, stream>>>(y, srcs, offs, dinv, W1, b1, W2,
                                                h2, n, E);
    agg2_fc<<<(n + AGG_NODES - 1) / AGG_NODES, 256, 0, stream>>>(
        h2, srcs, offs, dinv, b2, fcW1, fcb1, fcW2, fcb2, out, n, E);
}

// Round 20
// 176.975 us; speedup vs baseline: 3.4141x; 1.0119x over previous
//
#include <hip/hip_runtime.h>

// ---------------------------------------------------------------------------
// GCN pipeline, round 20 (round-19 structure; y table also fp16):
//   histA -> scanTiles -> multisplit2 -> place_fine2 (y in fp16, 16B rows)
//   -> agg1_t12 (single 16B half8 load per edge, fp32 accumulate, fused
//   W1/relu/W2, h2 out fp16) -> agg2_fc (fp16 h2 gathers + FC head).
// Round-19 validated precision-for-bandwidth: fp16 h2 won 5.2us with zero
// absmax movement. Same lever on y: 2 loads/edge -> 1, table 3.2->1.6MB.
// Accumulation stays fp32 everywhere.
// ---------------------------------------------------------------------------

#define MS_TILE 2048
#define MAXB 512  // padded coarse-bucket count (NBkt = ceil(n/256) <= 512)
#define AGG_NODES 32
#define AGG_STAGE 1024

typedef __attribute__((ext_vector_type(4))) _Float16 half4;
typedef __attribute__((ext_vector_type(8))) _Float16 half8;

// Inclusive shfl scan across the wave; then cross-wave combine via wsum[4].
__device__ inline int scan256_incl(int v, int lane, int w, int* wsum,
                                   int* total) {
    int incl = v;
#pragma unroll
    for (int d = 1; d < 64; d <<= 1) {
        int up = __shfl_up(incl, d, 64);
        if (lane >= d) incl += up;
    }
    if (lane == 63) wsum[w] = incl;
    __syncthreads();
    int add = 0;
    if (w > 0) add += wsum[0];
    if (w > 1) add += wsum[1];
    if (w > 2) add += wsum[2];
    *total = wsum[0] + wsum[1] + wsum[2] + wsum[3];
    return incl + add;
}

// per-tile LDS histogram of dst>>8 -> histG[tile*512 + b] (coalesced rows)
__global__ __launch_bounds__(256) void histA(const int* __restrict__ dst,
                                             int* __restrict__ histG, int E) {
    __shared__ int h[MAXB];
    int t = threadIdx.x;
    h[t] = 0;
    h[t + 256] = 0;
    __syncthreads();
    int base = blockIdx.x * MS_TILE;
    int cnt = min(MS_TILE, E - base);
    for (int k = t; k < cnt; k += 256) atomicAdd(&h[dst[base + k] >> 8], 1);
    __syncthreads();
    histG[blockIdx.x * MAXB + t] = h[t];
    histG[blockIdx.x * MAXB + 256 + t] = h[t + 256];
}

// one block per bucket b: exclusive scan of histG[.][b] across tiles
__global__ __launch_bounds__(256) void scanTiles(const int* __restrict__ histG,
                                                 int* __restrict__ offsG,
                                                 int* __restrict__ bucketTotal,
                                                 int nTiles) {
    __shared__ int wsum[4];
    int b = blockIdx.x, t = threadIdx.x;
    int lane = t & 63, w = t >> 6;
    int run = 0;
    for (int base = 0; base < nTiles; base += 256) {
        int idx = base + t;
        int v = (idx < nTiles) ? histG[idx * MAXB + b] : 0;
        int total;
        int incl = scan256_incl(v, lane, w, wsum, &total);
        if (idx < nTiles) offsG[idx * MAXB + b] = incl - v + run;
        run += total;
        __syncthreads();
    }
    if (t == 0) bucketTotal[b] = run;
}

// Deterministic tile counting-sort. Payload: (src<<8)|(dst&255).
__global__ __launch_bounds__(256) void multisplit2(
    const int* __restrict__ src, const int* __restrict__ dst,
    const int* __restrict__ histG, const int* __restrict__ offsG,
    const int* __restrict__ btot, int* __restrict__ gbaseOut,
    unsigned* __restrict__ binned, int E) {
    __shared__ unsigned stage[MS_TILE];
    __shared__ unsigned short sb[MS_TILE];
    __shared__ int hoff[MAXB + 1];
    __shared__ int hcur[MAXB];
    __shared__ int gb[MAXB];
    __shared__ int wsum[4];
    int t = threadIdx.x;
    int lane = t & 63, w = t >> 6;
    int tile = blockIdx.x;
    int base = tile * MS_TILE;
    int cnt = min(MS_TILE, E - base);

    int b0 = btot[2 * t], b1v = btot[2 * t + 1];
    int s2 = b0 + b1v;
    int tot2;
    int incl2 = scan256_incl(s2, lane, w, wsum, &tot2);
    int ex2 = incl2 - s2;
    gb[2 * t] = ex2 + offsG[tile * MAXB + 2 * t];
    gb[2 * t + 1] = ex2 + b0 + offsG[tile * MAXB + 2 * t + 1];
    if (tile == 0) {
        gbaseOut[2 * t] = ex2;
        gbaseOut[2 * t + 1] = ex2 + b0;
        if (t == 255) gbaseOut[MAXB] = E;
    }
    __syncthreads();

    int a0 = histG[tile * MAXB + 2 * t];
    int a1 = histG[tile * MAXB + 2 * t + 1];
    int s = a0 + a1;
    int tot;
    int incl = scan256_incl(s, lane, w, wsum, &tot);
    int ex = incl - s;
    hoff[2 * t] = ex;
    hoff[2 * t + 1] = ex + a0;
    hcur[2 * t] = ex;
    hcur[2 * t + 1] = ex + a0;
    if (t == 255) hoff[MAXB] = cnt;
    __syncthreads();
    for (int k = t; k < cnt; k += 256) {
        int d = dst[base + k];
        int b = d >> 8;
        int p = atomicAdd(&hcur[b], 1);
        stage[p] = ((unsigned)src[base + k] << 8) | (unsigned)(d & 255);
        sb[p] = (unsigned short)b;
    }
    __syncthreads();
    for (int k = t; k < cnt; k += 256) {
        int b = sb[k];
        binned[gb[b] + (k - hoff[b])] = stage[k];
    }
}

// Per coarse bucket: per-node deg via LDS count, shfl scan -> offs, dinv,
// y[i,:] = dinv[i]*x[i,:] (8 fp16 = 16B rows), then exact CSR scatter.
__global__ __launch_bounds__(256) void place_fine2(
    const unsigned* __restrict__ binned, const int* __restrict__ gbase,
    const float* __restrict__ x, int* __restrict__ offs,
    float* __restrict__ dinv, _Float16* __restrict__ y, int* __restrict__ srcs,
    int n) {
    __shared__ int cnt[256];
    __shared__ int lcur[256];
    __shared__ int wsum[4];
    int t = threadIdx.x, b = blockIdx.x;
    int lane = t & 63, w = t >> 6;
    int node0 = b << 8;
    int nn = min(256, n - node0);
    int e0 = gbase[b], e1 = gbase[b + 1];
    cnt[t] = 0;
    __syncthreads();
    for (int k = e0 + t; k < e1; k += 256) atomicAdd(&cnt[binned[k] & 255u], 1);
    __syncthreads();
    int c = cnt[t];
    int tot;
    int incl = scan256_incl(c, lane, w, wsum, &tot);
    int myoff = e0 + (incl - c);
    lcur[t] = myoff;
    if (t < nn) {
        int node = node0 + t;
        offs[node] = myoff;
        float di = 1.0f / sqrtf((float)(c + 1));  // +1 self loop
        dinv[node] = di;
        const float* xr = x + (size_t)node * 5;
        half8 hv;
        hv[0] = (_Float16)(xr[0] * di);
        hv[1] = (_Float16)(xr[1] * di);
        hv[2] = (_Float16)(xr[2] * di);
        hv[3] = (_Float16)(xr[3] * di);
        hv[4] = (_Float16)(xr[4] * di);
        hv[5] = (_Float16)0.f;
        hv[6] = (_Float16)0.f;
        hv[7] = (_Float16)0.f;
        *(half8*)(y + (size_t)node * 8) = hv;
    }
    __syncthreads();
    for (int k = e0 + t; k < e1; k += 256) {
        unsigned wd = binned[k];
        int p = atomicAdd(&lcur[wd & 255u], 1);
        srcs[p] = (int)(wd >> 8);
    }
}

// FUSED layer-1 aggregate + both transforms, 32-node blocks (3125 blocks).
// Gather: 8 threads/node, ONE 16B half8 load per edge, fp32 accumulate,
// shfl-xor reduce; z in LDS. h2 written as fp16.
__global__ __launch_bounds__(256) void agg1_t12(
    const _Float16* __restrict__ y, const int* __restrict__ srcs,
    const int* __restrict__ offs, const float* __restrict__ dinv,
    const float* __restrict__ W1, const float* __restrict__ b1,
    const float* __restrict__ W2, _Float16* __restrict__ h2, int n, int E) {
    __shared__ float w1s[320];
    __shared__ float b1s[64];
    __shared__ float w2s[64 * 32];
    __shared__ float o1[32 * 64];
    __shared__ float zs[32 * 6];
    int t = threadIdx.x;
    w1s[t] = W1[t];
    if (t < 64) {
        w1s[t + 256] = W1[t + 256];
        b1s[t] = b1[t];
    }
#pragma unroll
    for (int r = 0; r < 8; ++r) w2s[r * 256 + t] = W2[r * 256 + t];

    int node0 = blockIdx.x * 32;
    int li = t >> 3, e = t & 7;
    int i = node0 + li;
    const half8* yv = (const half8*)y;
    float a0 = 0.f, a1 = 0.f, a2 = 0.f, a3 = 0.f, a4 = 0.f;
    if (i < n) {
        int off = offs[i];
        int cnt = ((i + 1 < n) ? offs[i + 1] : E) - off;
        if (e == 0) {  // self-loop term once per node
            half8 v = yv[i];
            a0 = (float)v[0]; a1 = (float)v[1]; a2 = (float)v[2];
            a3 = (float)v[3]; a4 = (float)v[4];
        }
        for (int p = e; p < cnt; p += 8) {
            half8 v = yv[srcs[off + p]];
            a0 += (float)v[0]; a1 += (float)v[1]; a2 += (float)v[2];
            a3 += (float)v[3]; a4 += (float)v[4];
        }
    }
#pragma unroll
    for (int m = 4; m >= 1; m >>= 1) {
        a0 += __shfl_xor(a0, m, 64);
        a1 += __shfl_xor(a1, m, 64);
        a2 += __shfl_xor(a2, m, 64);
        a3 += __shfl_xor(a3, m, 64);
        a4 += __shfl_xor(a4, m, 64);
    }
    if (i < n && e == 0) {
        float di = dinv[i];
        zs[li * 6 + 0] = a0 * di;
        zs[li * 6 + 1] = a1 * di;
        zs[li * 6 + 2] = a2 * di;
        zs[li * 6 + 3] = a3 * di;
        zs[li * 6 + 4] = a4 * di;
        zs[li * 6 + 5] = di;
    }
    __syncthreads();
#pragma unroll
    for (int r = 0; r < 8; ++r) {
        int idx = r * 256 + t;
        int lj = idx >> 6, f = idx & 63;
        if (node0 + lj < n) {
            const float* zr = zs + lj * 6;
            float acc = b1s[f];
#pragma unroll
            for (int k = 0; k < 5; ++k) acc += zr[k] * w1s[k * 64 + f];
            o1[lj * 64 + f] = fmaxf(acc, 0.0f);
        }
    }
    __syncthreads();
#pragma unroll
    for (int r = 0; r < 4; ++r) {
        int idx = r * 256 + t;
        int lj = idx >> 5, g = idx & 31;
        int i2 = node0 + lj;
        if (i2 < n) {
            float acc = 0.f;
#pragma unroll
            for (int k = 0; k < 64; ++k) acc += o1[lj * 64 + k] * w2s[k * 32 + g];
            h2[(size_t)i2 * 32 + g] = (_Float16)(acc * zs[lj * 6 + 5]);
        }
    }
}

// FUSED layer-2 aggregate + FC head. fp16 h2 rows (64B), 8 threads/node
// each gathering 8B (half4); fp32 accumulation; LDS-staged CSR indices.
__global__ __launch_bounds__(256) void agg2_fc(
    const _Float16* __restrict__ h, const int* __restrict__ srcs,
    const int* __restrict__ offs, const float* __restrict__ dinv,
    const float* __restrict__ b2, const float* __restrict__ fcW1,
    const float* __restrict__ fcb1, const float* __restrict__ fcW2,
    const float* __restrict__ fcb2, float* __restrict__ out, int n, int E) {
    __shared__ int sidx[AGG_STAGE];
    __shared__ float sm[AGG_NODES * 33];
    __shared__ float x3s[AGG_NODES * 16];
    __shared__ float w1s[512];
    __shared__ float w2s[32];
    __shared__ float b1s[16];
    __shared__ float b2s[2];
    __shared__ float bs2[32];
    int t = threadIdx.x;
    w1s[t] = fcW1[t];
    w1s[t + 256] = fcW1[t + 256];
    if (t < 32) { w2s[t] = fcW2[t]; bs2[t] = b2[t]; }
    if (t < 16) b1s[t] = fcb1[t];
    if (t < 2) b2s[t] = fcb2[t];

    int node0 = blockIdx.x * AGG_NODES;
    int li = t >> 3, fq = t & 7;
    int i = node0 + li;
    bool live = (i < n);
    const char* hb = (const char*)h;

    int e0 = offs[node0];
    int eEnd = (node0 + AGG_NODES < n) ? offs[node0 + AGG_NODES] : E;
    int myOff = 0, myCnt = 0;
    float4 acc = {0.f, 0.f, 0.f, 0.f};
    if (live) {
        myOff = offs[i];
        myCnt = ((i + 1 < n) ? offs[i + 1] : E) - myOff;
        half4 sv = *(const half4*)(hb + ((size_t)i << 6) + (fq << 3));
        acc.x = (float)sv.x; acc.y = (float)sv.y;
        acc.z = (float)sv.z; acc.w = (float)sv.w;
    }

    for (int cs = e0; cs < eEnd; cs += AGG_STAGE) {
        int ce = min(cs + AGG_STAGE, eEnd);
        for (int k = cs + t; k < ce; k += 256) sidx[k - cs] = srcs[k] << 6;
        __syncthreads();
        int ps = max(myOff, cs), pe = min(myOff + myCnt, ce);
        int p = ps;
        for (; p + 8 <= pe; p += 8) {
            int o[8];
#pragma unroll
            for (int u = 0; u < 8; ++u) o[u] = sidx[p + u - cs];
            half4 v[8];
#pragma unroll
            for (int u = 0; u < 8; ++u)
                v[u] = *(const half4*)(hb + o[u] + (fq << 3));
#pragma unroll
            for (int u = 0; u < 8; ++u) {
                acc.x += (float)v[u].x; acc.y += (float)v[u].y;
                acc.z += (float)v[u].z; acc.w += (float)v[u].w;
            }
        }
        for (; p + 4 <= pe; p += 4) {
            int o0 = sidx[p - cs], o1 = sidx[p + 1 - cs];
            int o2 = sidx[p + 2 - cs], o3 = sidx[p + 3 - cs];
            half4 v0 = *(const half4*)(hb + o0 + (fq << 3));
            half4 v1 = *(const half4*)(hb + o1 + (fq << 3));
            half4 v2 = *(const half4*)(hb + o2 + (fq << 3));
            half4 v3 = *(const half4*)(hb + o3 + (fq << 3));
            acc.x += (float)v0.x + (float)v1.x + (float)v2.x + (float)v3.x;
            acc.y += (float)v0.y + (float)v1.y + (float)v2.y + (float)v3.y;
            acc.z += (float)v0.z + (float)v1.z + (float)v2.z + (float)v3.z;
            acc.w += (float)v0.w + (float)v1.w + (float)v2.w + (float)v3.w;
        }
        for (; p < pe; ++p) {
            half4 v = *(const half4*)(hb + sidx[p - cs] + (fq << 3));
            acc.x += (float)v.x; acc.y += (float)v.y;
            acc.z += (float)v.z; acc.w += (float)v.w;
        }
        __syncthreads();
    }

    if (live) {
        float di = dinv[i];
        int f0 = fq << 2;
        sm[li * 33 + f0 + 0] = fmaxf(di * acc.x + bs2[f0 + 0], 0.f);
        sm[li * 33 + f0 + 1] = fmaxf(di * acc.y + bs2[f0 + 1], 0.f);
        sm[li * 33 + f0 + 2] = fmaxf(di * acc.z + bs2[f0 + 2], 0.f);
        sm[li * 33 + f0 + 3] = fmaxf(di * acc.w + bs2[f0 + 3], 0.f);
    }
    __syncthreads();
#pragma unroll
    for (int r = 0; r < 2; ++r) {
        int idx = r * 256 + t;
        int lj = idx >> 4, j = idx & 15;
        if (node0 + lj < n) {
            float a = b1s[j];
#pragma unroll
            for (int k = 0; k < 32; ++k) a += sm[lj * 33 + k] * w1s[k * 16 + j];
            x3s[lj * 16 + j] = fmaxf(a, 0.f);
        }
    }
    __syncthreads();
    if (t < 64) {
        int lj = t >> 1, o = t & 1;
        if (node0 + lj < n) {
            float a = b2s[o];
#pragma unroll
            for (int j = 0; j < 16; ++j) a += x3s[lj * 16 + j] * w2s[j * 2 + o];
            out[(size_t)(node0 + lj) * 2 + o] = a;
        }
    }
}

extern "C" void kernel_launch(void* const* d_in, const int* in_sizes, int n_in,
                              void* d_out, int out_size, void* d_ws, size_t ws_size,
                              hipStream_t stream) {
    const float* edge_attr = (const float*)d_in[0];
    const int* edge_index  = (const int*)d_in[1];
    const float* W1   = (const float*)d_in[2];
    const float* b1   = (const float*)d_in[3];
    const float* W2   = (const float*)d_in[4];
    const float* b2   = (const float*)d_in[5];
    const float* fcW1 = (const float*)d_in[6];
    const float* fcb1 = (const float*)d_in[7];
    const float* fcW2 = (const float*)d_in[8];
    const float* fcb2 = (const float*)d_in[9];
    float* out = (float*)d_out;

    int n = in_sizes[0] / 5;
    int E = in_sizes[1] / 2;
    int NBkt = (n + 255) >> 8;                 // 391 for n=100000 (<= MAXB)
    int nTiles = (E + MS_TILE - 1) / MS_TILE;  // 782
    const int* src = edge_index;
    const int* dst = edge_index + E;

    char* ws = (char*)d_ws;
    auto alloc = [&](size_t bytes) {
        char* p = ws;
        ws += (bytes + 255) & ~(size_t)255;
        return p;
    };
    int*      offs   = (int*)alloc((size_t)n * 4);
    float*    dinv   = (float*)alloc((size_t)n * 4);
    int*      histG  = (int*)alloc((size_t)nTiles * MAXB * 4);
    int*      offsG  = (int*)alloc((size_t)nTiles * MAXB * 4);
    int*      btot   = (int*)alloc((size_t)MAXB * 4);
    int*      gbase  = (int*)alloc((size_t)(MAXB + 1) * 4);
    int*      srcs   = (int*)alloc((size_t)E * 4);
    unsigned* binned = (unsigned*)alloc((size_t)E * 4);
    _Float16* y      = (_Float16*)alloc((size_t)n * 8 * 2);
    _Float16* h2     = (_Float16*)alloc((size_t)n * 32 * 2);

    histA<<<nTiles, 256, 0, stream>>>(dst, histG, E);
    scanTiles<<<MAXB, 256, 0, stream>>>(histG, offsG, btot, nTiles);
    multisplit2<<<nTiles, 256, 0, stream>>>(src, dst, histG, offsG, btot, gbase,
                                            binned, E);
    place_fine2<<<NBkt, 256, 0, stream>>>(binned, gbase, edge_attr, offs, dinv,
                                          y, srcs, n);
    agg1_t12<<<(n + 31) / 32, 256, 0, stream>>>(y, srcs, offs, dinv, W1, b1, W2,
                                                h2, n, E);
    agg2_fc<<<(n + AGG_NODES - 1) / AGG_NODES, 256, 0, stream>>>(
        h2, srcs, offs, dinv, b2, fcW1, fcb1, fcW2, fcb2, out, n, E);
}